// Round 13
// baseline (23.394 us; speedup 1.0000x reference)
//
#include <hip/hip_runtime.h>
#include <hip/hip_bf16.h>
#include <utility>

using floatx4 = __attribute__((ext_vector_type(4))) float;
using shortx8 = __attribute__((ext_vector_type(8))) short;

constexpr int M = 32, N = 4096, K = 4096;
constexpr int WAVES = 8;              // waves per block
constexpr int WSPAN = K / WAVES;      // 512 k per wave
constexpr int CH = 64;                // k per chunk
constexpr int NCH = WSPAN / CH;       // 8 chunks per wave
constexpr int RING = 4;               // LDS ring slots per wave

__device__ __forceinline__ void dma16(const float* g, char* l) {
    __builtin_amdgcn_global_load_lds(
        (const __attribute__((address_space(1))) unsigned int*)g,
        (__attribute__((address_space(3))) unsigned int*)l, 16, 0, 0);
}

// ---- init: pack x into fragment-ordered bf16 (proven R8 path).
// layout: [kblk(128)][half(2)][lane(64)][j(8)] shorts; lane L holds
// batch b = half*16 + (L&15), k = kblk*32 + (L>>4)*8 + j.
__global__ __launch_bounds__(256) void pack_x(
    const float* __restrict__ x, short* __restrict__ xfrag)
{
    int g = blockIdx.x * blockDim.x + threadIdx.x;   // 16384 threads
    int kblk = g >> 7, rem = g & 127;
    int half = rem >> 6, lane = rem & 63;
    int b = half * 16 + (lane & 15);
    int k = kblk * 32 + (lane >> 4) * 8;
    const float* src = x + (size_t)b * K + k;
    shortx8 v;
    #pragma unroll
    for (int j = 0; j < 8; ++j) {
        __hip_bfloat16 h = __float2bfloat16(src[j]);
        v[j] = *reinterpret_cast<short*>(&h);
    }
    *reinterpret_cast<shortx8*>(xfrag + (size_t)g * 8) = v;
}

// ---- main GEMM: 256 blocks (16 o-rows) x 512 threads (8 waves).
// W: global_load_lds DMA (16B/lane) -> ring-4 wave-private LDS, linear dest
// with inverse-XOR-swizzled global source; dequant at read time.
// x: xfrag register loads, ring-4. Counted vmcnt (T4), no barriers in loop.
__global__ __launch_bounds__(512, 2) void gemm_main(
    const float* __restrict__ W, const float* __restrict__ scales,
    const short* __restrict__ xfrag, const float* __restrict__ tscale,
    const float* __restrict__ bias, float* __restrict__ out)
{
    __shared__ __align__(16) char lds[WAVES * RING * 4096];   // 128 KB

    const int t    = threadIdx.x;
    const int lane = t & 63;
    const int wave = t >> 6;
    const int o0   = blockIdx.x * 16;
    const int kw0  = wave * WSPAN;

    const float rt = 1.0f / tscale[0];
    const int fr = lane & 15, kg = lane >> 4;

    char* mybuf = lds + wave * (RING * 4096);

    shortx8 xa[RING][2], xb[RING][2];
    float  ssc[RING][2];

    // --- DMA one 4KB chunk (16 rows x 64k f32) into ring slot.
    // Instruction j writes LDS rows [4j,4j+4) linearly (lane -> base+lane*16).
    // Global source pre-swizzled: lane L covers seg = ((L&15) ^ row) & 15, so
    // LDS slot s of row r holds W granule (s ^ r) & 15.
    auto issueW = [&](int c) {
        char* buf = mybuf + (c & (RING - 1)) * 4096;
        const int kc = kw0 + c * CH;
        #pragma unroll
        for (int j = 0; j < 4; ++j) {
            int row = j * 4 + (lane >> 4);
            int seg = ((lane & 15) ^ row) & 15;
            dma16(W + (size_t)(o0 + row) * K + kc + seg * 4, buf + j * 1024);
        }
        __builtin_amdgcn_sched_barrier(0);
    };
    auto loadX = [&](int c) {
        const int sl = c & (RING - 1);
        const int kb0 = (kw0 + c * CH) >> 5;
        #pragma unroll
        for (int b = 0; b < 2; ++b) {
            xa[sl][b] = *reinterpret_cast<const shortx8*>(
                xfrag + ((size_t)(kb0 + b) * 2 + 0) * 512 + lane * 8);
            xb[sl][b] = *reinterpret_cast<const shortx8*>(
                xfrag + ((size_t)(kb0 + b) * 2 + 1) * 512 + lane * 8);
        }
        // scales this lane needs: row fr, blocks (kc>>4) + b*2 + (kg>>1)
        const int kc = kw0 + c * CH;
        const float* sb = scales + (size_t)(o0 + fr) * (K / 16) + (kc >> 4) + (kg >> 1);
        ssc[sl][0] = sb[0];
        ssc[sl][1] = sb[2];
        __builtin_amdgcn_sched_barrier(0);
    };

    floatx4 acc0 = {0.f, 0.f, 0.f, 0.f};
    floatx4 acc1 = {0.f, 0.f, 0.f, 0.f};

    // ---- prologue: x/sc for chunks 0,1; DMA chunks 0,1,2 ----
    loadX(0);
    loadX(1);
    issueW(0);
    issueW(1);
    issueW(2);

    // vmcnt immediates per iteration (issue order pinned by sched_barriers):
    // steady N=24 = DMA(c+1..c+3)=12 + x/sc(c+1)=6 + x/sc(c+2)=6.
    constexpr int NC[8] = {18, 24, 24, 24, 24, 20, 10, 0};

    auto chunk = [&](auto cc) {
        constexpr int c = cc.value;
        if constexpr (c + 2 < NCH) loadX(c + 2);
        if constexpr (c + 3 < NCH) issueW(c + 3);
        asm volatile("s_waitcnt vmcnt(%0)" :: "i"(NC[c]) : "memory");
        __builtin_amdgcn_sched_barrier(0);

        const int sl = c & (RING - 1);
        char* buf = mybuf + sl * 4096;
        #pragma unroll
        for (int b = 0; b < 2; ++b) {          // 2 k-steps of 32
            const float rs = rt * __builtin_amdgcn_rcpf(ssc[sl][b]);
            int q0 = b * 8 + kg * 2;
            floatx4 v0 = *reinterpret_cast<const floatx4*>(
                buf + fr * 256 + ((q0 ^ fr) & 15) * 16);
            floatx4 v1 = *reinterpret_cast<const floatx4*>(
                buf + fr * 256 + (((q0 + 1) ^ fr) & 15) * 16);
            shortx8 wf;
            #pragma unroll
            for (int j = 0; j < 4; ++j) {
                __hip_bfloat16 h0 = __float2bfloat16(v0[j] * rs);
                __hip_bfloat16 h1 = __float2bfloat16(v1[j] * rs);
                wf[j]     = *reinterpret_cast<short*>(&h0);
                wf[j + 4] = *reinterpret_cast<short*>(&h1);
            }
            acc0 = __builtin_amdgcn_mfma_f32_16x16x32_bf16(xa[sl][b], wf, acc0, 0, 0, 0);
            acc1 = __builtin_amdgcn_mfma_f32_16x16x32_bf16(xb[sl][b], wf, acc1, 0, 0, 0);
        }
    };

    chunk(std::integral_constant<int, 0>{});
    chunk(std::integral_constant<int, 1>{});
    chunk(std::integral_constant<int, 2>{});
    chunk(std::integral_constant<int, 3>{});
    chunk(std::integral_constant<int, 4>{});
    chunk(std::integral_constant<int, 5>{});
    chunk(std::integral_constant<int, 6>{});
    chunk(std::integral_constant<int, 7>{});

    // ---- in-block reduce across 8 waves (reuse LDS) ----
    __syncthreads();
    float* red = (float*)lds;               // [wave][e(0..7)][lane] = 16 KB
    #pragma unroll
    for (int r = 0; r < 4; ++r) {
        red[(wave * 8 + r) * 64 + lane]     = acc0[r];
        red[(wave * 8 + 4 + r) * 64 + lane] = acc1[r];
    }
    __syncthreads();

    // t -> (b = t>>4, oc = t&15); b = hi*16 + kgq*4 + r;
    // value at red[w][hi*4+r][kgq*16+oc]
    {
        int b = t >> 4, oc = t & 15;
        int hi = b >> 4, kgq = (b >> 2) & 3, r = b & 3;
        int e = hi * 4 + r, ls = kgq * 16 + oc;
        float v = bias[o0 + oc];
        #pragma unroll
        for (int w = 0; w < WAVES; ++w)
            v += red[(w * 8 + e) * 64 + ls];
        out[(size_t)b * N + o0 + oc] = v;
    }
}

// ---- fallback (tiny ws): atomic split-K, x as f32
__global__ __launch_bounds__(256) void init_bias(
    const float* __restrict__ bias, float* __restrict__ out)
{
    int i = blockIdx.x * blockDim.x + threadIdx.x;
    if (i < M * N) out[i] = bias[i & (N - 1)];
}

__global__ __launch_bounds__(256) void gemm_atomic(
    const float* __restrict__ W, const float* __restrict__ scales,
    const float* __restrict__ xf32, const float* __restrict__ tscale,
    float* __restrict__ out)
{
    const int lane = threadIdx.x & 63;
    const int wave = threadIdx.x >> 6;
    const int o0 = blockIdx.x * 64 + wave * 16;
    const int k0 = blockIdx.y * 128;
    const int row = lane & 15, kg = lane >> 4;

    const float* wp  = W + (size_t)(o0 + row) * K + k0 + kg * 8;
    const float* sp  = scales + (size_t)(o0 + row) * (K / 16) + (k0 >> 4) + (kg >> 1);
    const float* xf0 = xf32 + (size_t)row * K + k0 + kg * 8;
    const float* xf1 = xf32 + (size_t)(row + 16) * K + k0 + kg * 8;
    const float rt = 1.0f / tscale[0];

    floatx4 acc0 = {0.f, 0.f, 0.f, 0.f};
    floatx4 acc1 = {0.f, 0.f, 0.f, 0.f};
    for (int i = 0; i < 4; ++i) {
        floatx4 w0 = *reinterpret_cast<const floatx4*>(wp + i * 32);
        floatx4 w1 = *reinterpret_cast<const floatx4*>(wp + i * 32 + 4);
        float s = sp[2 * i];
        shortx8 xav, xbv, wf;
        const float rs = rt / s;
        #pragma unroll
        for (int j = 0; j < 8; ++j) {
            float a = xf0[i * 32 + j], bb = xf1[i * 32 + j];
            float wv = (j < 4 ? w0[j] : w1[j - 4]) * rs;
            __hip_bfloat16 ha = __float2bfloat16(a);
            __hip_bfloat16 hb = __float2bfloat16(bb);
            __hip_bfloat16 hw = __float2bfloat16(wv);
            xav[j] = *reinterpret_cast<short*>(&ha);
            xbv[j] = *reinterpret_cast<short*>(&hb);
            wf[j]  = *reinterpret_cast<short*>(&hw);
        }
        acc0 = __builtin_amdgcn_mfma_f32_16x16x32_bf16(xav, wf, acc0, 0, 0, 0);
        acc1 = __builtin_amdgcn_mfma_f32_16x16x32_bf16(xbv, wf, acc1, 0, 0, 0);
    }
    float* op0 = out + (size_t)(kg * 4) * N + o0 + row;
    float* op1 = out + (size_t)(16 + kg * 4) * N + o0 + row;
    #pragma unroll
    for (int r = 0; r < 4; ++r) {
        atomicAdd(op0 + (size_t)r * N, acc0[r]);
        atomicAdd(op1 + (size_t)r * N, acc1[r]);
    }
}

extern "C" void kernel_launch(void* const* d_in, const int* in_sizes, int n_in,
                              void* d_out, int out_size, void* d_ws, size_t ws_size,
                              hipStream_t stream)
{
    const float* x      = (const float*)d_in[0];
    const float* W      = (const float*)d_in[1];
    const float* tscale = (const float*)d_in[2];
    const float* scales = (const float*)d_in[3];
    const float* bias   = (const float*)d_in[4];
    float* out = (float*)d_out;

    const size_t xfrag_bytes = (size_t)M * K * sizeof(short);   // 256 KiB

    if (ws_size >= xfrag_bytes) {
        short* xfrag = (short*)d_ws;
        pack_x<<<(M * K / 8 + 255) / 256, 256, 0, stream>>>(x, xfrag);
        gemm_main<<<N / 16, 512, 0, stream>>>(W, scales, xfrag, tscale, bias, out);
    } else {
        init_bias<<<(M * N + 255) / 256, 256, 0, stream>>>(bias, out);
        dim3 grid(N / 64, K / 128);
        gemm_atomic<<<grid, 256, 0, stream>>>(W, scales, x, tscale, out);
    }
}